// Round 2
// baseline (235.309 us; speedup 1.0000x reference)
//
#include <hip/hip_runtime.h>

#define B_   64
#define L_   2048
#define D_   512
#define SEG_ 16         // segments over L for the two gather passes
#define RPS_ 128        // rows per segment (L_/SEG_)
#define NS_  8          // LDS ring slots per wave (1KB bf16 row each)
#define NROW_ 50258     // vocab+1
#define TOTE_ (NROW_ * D_)   // 25,732,096 elements

// counted vmem wait; "memory" clobber keeps following ds_read from hoisting
#define WAITVM(N) asm volatile("s_waitcnt vmcnt(" #N ")" ::: "memory")

// async global->LDS DMA: 16B/lane, 64 lanes -> 1KB (= one bf16 row) per call
__device__ __forceinline__ void gl2lds(const void* g, void* l) {
  __builtin_amdgcn_global_load_lds(
      (const __attribute__((address_space(1))) void*)g,
      (__attribute__((address_space(3))) void*)l, 16, 0, 0);
}

// DPP add step: x += dpp_move(x, C); bound_ctrl -> invalid lanes contribute 0
template <int C>
__device__ __forceinline__ float dpp_add(float x) {
  int y = __builtin_amdgcn_update_dpp(0, __builtin_bit_cast(int, x), C, 0xf, 0xf, true);
  return x + __builtin_bit_cast(float, y);
}

// full 64-lane sum, VALU-pipe only; uniform result via readlane 63
__device__ __forceinline__ float wave_sum_u(float x) {
  x = dpp_add<0x111>(x);   // row_shr:1
  x = dpp_add<0x112>(x);   // row_shr:2
  x = dpp_add<0x114>(x);   // row_shr:4
  x = dpp_add<0x118>(x);   // row_shr:8
  x = dpp_add<0x142>(x);   // row_bcast15
  x = dpp_add<0x143>(x);   // row_bcast31 -> lane 63 has full sum
  return __builtin_bit_cast(float, __builtin_amdgcn_readlane(__builtin_bit_cast(int, x), 63));
}

__device__ __forceinline__ float blo(unsigned u) {
  return __builtin_bit_cast(float, u << 16);
}
__device__ __forceinline__ float bhi(unsigned u) {
  return __builtin_bit_cast(float, u & 0xffff0000u);
}
// unpack 8 bf16 (16B) into fp32
__device__ __forceinline__ void unpk8(uint4 q, float* f) {
  f[0] = blo(q.x); f[1] = bhi(q.x);
  f[2] = blo(q.y); f[3] = bhi(q.y);
  f[4] = blo(q.z); f[5] = bhi(q.z);
  f[6] = blo(q.w); f[7] = bhi(q.w);
}
// RNE fp32 -> bf16 pair packed into one uint (a = low ushort, b = high)
__device__ __forceinline__ unsigned pkbf(float a, float b) {
  unsigned ua = __builtin_bit_cast(unsigned, a);
  unsigned ub = __builtin_bit_cast(unsigned, b);
  ua += 0x7fffu + ((ua >> 16) & 1u);
  ub += 0x7fffu + ((ub >> 16) & 1u);
  return (ua >> 16) | (ub & 0xffff0000u);
}

// ---------- K0: convert fp32 table -> bf16 table (RNE) ----------
__global__ __launch_bounds__(256) void k_cvt(const float* __restrict__ emb,
                                             ushort* __restrict__ dst) {
  const size_t stride = (size_t)gridDim.x * blockDim.x * 8;
  for (size_t p = ((size_t)blockIdx.x * blockDim.x + threadIdx.x) * 8;
       p < (size_t)TOTE_; p += stride) {
    const float4 x0 = *(const float4*)(emb + p);
    const float4 x1 = *(const float4*)(emb + p + 4);
    uint4 o;
    o.x = pkbf(x0.x, x0.y); o.y = pkbf(x0.z, x0.w);
    o.z = pkbf(x1.x, x1.y); o.w = pkbf(x1.z, x1.w);
    *(uint4*)(dst + p) = o;
  }
}

// tail-drain wait schedule for the NS_=8 ring (issued = min(i+8,32))
__device__ __forceinline__ void ring_wait(int i) {
  if (i < 25)       WAITVM(7);
  else if (i == 25) WAITVM(6);
  else if (i == 26) WAITVM(5);
  else if (i == 27) WAITVM(4);
  else if (i == 28) WAITVM(3);
  else if (i == 29) WAITVM(2);
  else if (i == 30) WAITVM(1);
  else              WAITVM(0);
}

// ---------- K1: partial sums of bf16 embedding rows (for h) ----------
// grid (SEG_, B_) = 1024 blocks, 4 waves. Per wave: 32 rows through a
// private 8-slot LDS ring, one 1KB global_load_lds per row.
__global__ __launch_bounds__(256) void k_hpart(const int* __restrict__ tok,
                                               const ushort* __restrict__ embh,
                                               float* __restrict__ A) {
  const int seg = blockIdx.x, b = blockIdx.y;
  const int t = threadIdx.x, w = t >> 6, lane = t & 63;
  __shared__ ushort stag[4 * NS_ * D_];          // 32 KB: 4 waves x 8 x 1KB
  ushort* wsl = stag + w * (NS_ * D_);
  const int tokv = tok[b * L_ + seg * RPS_ + w * 32 + (lane & 31)];
  float acc[8];
#pragma unroll
  for (int j = 0; j < 8; ++j) acc[j] = 0.f;
#pragma unroll
  for (int i = 0; i < NS_; ++i) {
    const size_t row = (size_t)(__builtin_amdgcn_readlane(tokv, i) + 1);
    gl2lds(embh + row * D_ + lane * 8, wsl + i * D_);
  }
#pragma unroll
  for (int i = 0; i < 32; ++i) {
    ring_wait(i);
    const uint4 q = *(const uint4*)(wsl + (i & (NS_ - 1)) * D_ + lane * 8);
    float e[8]; unpk8(q, e);
#pragma unroll
    for (int j = 0; j < 8; ++j) acc[j] += e[j];
    if (i + NS_ < 32) {
      const size_t row = (size_t)(__builtin_amdgcn_readlane(tokv, i + NS_) + 1);
      gl2lds(embh + row * D_ + lane * 8, wsl + (i & (NS_ - 1)) * D_);
    }
  }
  __syncthreads();                                // ring idle before overlay
  float* buf = (float*)stag;                      // 4*D_ floats combine buffer
#pragma unroll
  for (int j = 0; j < 8; ++j) buf[w * D_ + lane * 8 + j] = acc[j];
  __syncthreads();
  const int c = 2 * t;
  const float s0 = buf[c] + buf[D_ + c] + buf[2 * D_ + c] + buf[3 * D_ + c];
  const float s1 = buf[c + 1] + buf[D_ + c + 1] + buf[2 * D_ + c + 1] + buf[3 * D_ + c + 1];
  float* o = A + ((size_t)seg * B_ + b) * D_;
  o[c] = s0; o[c + 1] = s1;
}

// ---------- K2: v[b] = W_b @ h[b] / L  (fp32 weights, fp32 h) ----------
__global__ __launch_bounds__(256) void k_v(const float* __restrict__ A,
                                           const float* __restrict__ Wb,
                                           float* __restrict__ v) {
  const int g = blockIdx.x, b = blockIdx.y;
  const int t = threadIdx.x, w = t >> 6, lane = t & 63;
  __shared__ float sh[D_];
  float s0 = 0.f, s1 = 0.f;
#pragma unroll
  for (int s = 0; s < SEG_; ++s) {
    const float* hp = A + ((size_t)s * B_ + b) * D_;
    s0 += hp[2 * t]; s1 += hp[2 * t + 1];
  }
  sh[2 * t] = s0; sh[2 * t + 1] = s1;
  __syncthreads();
  const float4* shv = (const float4*)sh;
  const float4 a0 = shv[lane];
  const float4 a1 = shv[lane + 64];
  const int d0 = g * 64 + w * 16;
#pragma unroll 4
  for (int i = 0; i < 16; ++i) {
    const int d = d0 + i;
    const float4* rp = (const float4*)(Wb + (size_t)d * D_);
    const float4 r0 = rp[lane], r1 = rp[lane + 64];
    const float dot = r0.x * a0.x + r0.y * a0.y + r0.z * a0.z + r0.w * a0.w +
                      r1.x * a1.x + r1.y * a1.y + r1.z * a1.z + r1.w * a1.w;
    const float r = wave_sum_u(dot);
    if (lane == 0) v[(size_t)b * D_ + d] = r * (1.f / (float)L_);
  }
}

// ---------- K3: fused scores+softmax+weighted-sum over bf16 rows ----------
__global__ __launch_bounds__(256) void k_flash(const int* __restrict__ tok,
                                               const ushort* __restrict__ embh,
                                               const float* __restrict__ v,
                                               float* __restrict__ A,
                                               float* __restrict__ ms) {
  const int seg = blockIdx.x, b = blockIdx.y;
  const int t = threadIdx.x, w = t >> 6, lane = t & 63;
  __shared__ ushort stag[4 * NS_ * D_];          // 32 KB ring, overlaid later
  __shared__ float red[4][2];
  ushort* wsl = stag + w * (NS_ * D_);
  const int tokv = tok[b * L_ + seg * RPS_ + w * 32 + (lane & 31)];
  // this lane's 8-col slice of v
  float va[8];
  {
    const float4* vv = (const float4*)(v + (size_t)b * D_);
    const float4 v0 = vv[2 * lane], v1 = vv[2 * lane + 1];
    va[0] = v0.x; va[1] = v0.y; va[2] = v0.z; va[3] = v0.w;
    va[4] = v1.x; va[5] = v1.y; va[6] = v1.z; va[7] = v1.w;
  }
  float m = -1e30f, s = 0.f;
  float acc[8];
#pragma unroll
  for (int j = 0; j < 8; ++j) acc[j] = 0.f;
#pragma unroll
  for (int i = 0; i < NS_; ++i) {
    const size_t row = (size_t)(__builtin_amdgcn_readlane(tokv, i) + 1);
    gl2lds(embh + row * D_ + lane * 8, wsl + i * D_);
  }
#pragma unroll
  for (int i = 0; i < 32; ++i) {
    ring_wait(i);
    const uint4 q = *(const uint4*)(wsl + (i & (NS_ - 1)) * D_ + lane * 8);
    float e[8]; unpk8(q, e);
    float d = e[0] * va[0] + e[1] * va[1] + e[2] * va[2] + e[3] * va[3] +
              e[4] * va[4] + e[5] * va[5] + e[6] * va[6] + e[7] * va[7];
    const float sc = wave_sum_u(d);
    const float mn = fmaxf(m, sc);
    const float al = __expf(m - mn);
    const float p  = __expf(sc - mn);
    s = s * al + p;
#pragma unroll
    for (int j = 0; j < 8; ++j) acc[j] = acc[j] * al + p * e[j];
    m = mn;
    if (i + NS_ < 32) {
      const size_t row = (size_t)(__builtin_amdgcn_readlane(tokv, i + NS_) + 1);
      gl2lds(embh + row * D_ + lane * 8, wsl + (i & (NS_ - 1)) * D_);
    }
  }
  if (lane == 0) { red[w][0] = m; red[w][1] = s; }
  __syncthreads();                                // ring idle + red visible
  const float M = fmaxf(fmaxf(red[0][0], red[1][0]), fmaxf(red[2][0], red[3][0]));
  const float scw = __expf(m - M);                // m wave-uniform
  float* buf = (float*)stag;                      // overlay ring
#pragma unroll
  for (int j = 0; j < 8; ++j) buf[w * D_ + lane * 8 + j] = acc[j] * scw;
  __syncthreads();
  const int c = 2 * t;
  const float o0 = buf[c] + buf[D_ + c] + buf[2 * D_ + c] + buf[3 * D_ + c];
  const float o1 = buf[c + 1] + buf[D_ + c + 1] + buf[2 * D_ + c + 1] + buf[3 * D_ + c + 1];
  float* oa = A + ((size_t)seg * B_ + b) * D_;    // A reuse: k_v already consumed it
  oa[c] = o0; oa[c + 1] = o1;
  if (t == 0) {
    float st = red[0][1] * __expf(red[0][0] - M) + red[1][1] * __expf(red[1][0] - M)
             + red[2][1] * __expf(red[2][0] - M) + red[3][1] * __expf(red[3][0] - M);
    ms[((size_t)seg * B_ + b) * 2]     = M;
    ms[((size_t)seg * B_ + b) * 2 + 1] = st;
  }
}

// ---------- K4: merge segment partials -> out ----------
__global__ __launch_bounds__(256) void k_merge(const float* __restrict__ A,
                                               const float* __restrict__ ms,
                                               float* __restrict__ out) {
  const int b = blockIdx.x;
  const int t = threadIdx.x;
  __shared__ float wseg[SEG_];
  if (t == 0) {
    float M = -1e30f;
#pragma unroll
    for (int s = 0; s < SEG_; ++s) M = fmaxf(M, ms[((size_t)s * B_ + b) * 2]);
    float den = 0.f;
#pragma unroll
    for (int s = 0; s < SEG_; ++s)
      den += ms[((size_t)s * B_ + b) * 2 + 1] * __expf(ms[((size_t)s * B_ + b) * 2] - M);
    const float inv = 1.f / den;
#pragma unroll
    for (int s = 0; s < SEG_; ++s)
      wseg[s] = __expf(ms[((size_t)s * B_ + b) * 2] - M) * inv;
  }
  __syncthreads();
  const int c = 2 * t;
  float o0 = 0.f, o1 = 0.f;
#pragma unroll
  for (int s = 0; s < SEG_; ++s) {
    const float* oa = A + ((size_t)s * B_ + b) * D_;
    const float ww = wseg[s];
    o0 += ww * oa[c]; o1 += ww * oa[c + 1];
  }
  out[(size_t)b * D_ + c] = o0;
  out[(size_t)b * D_ + c + 1] = o1;
}

// ---------- launch ----------
extern "C" void kernel_launch(void* const* d_in, const int* in_sizes, int n_in,
                              void* d_out, int out_size, void* d_ws, size_t ws_size,
                              hipStream_t stream) {
  const int* tok = (const int*)d_in[0];
  const float* emb = (const float*)d_in[1];
  const float* Wb  = (const float*)d_in[2];
  float* out = (float*)d_out;
  float* ws = (float*)d_ws;

  // ws layout (floats): [bf16 table: 12,866,048][A: 524288][v: 32768][ms: 2048]
  ushort* embh = (ushort*)ws;                    // 50258*512 bf16 = 51.46 MB
  float* A  = ws + 12866048;
  float* v  = A + 524288;
  float* ms = v + 32768;                         // total ~53.7 MB of ws

  k_cvt  <<<4096,           256, 0, stream>>>(emb, embh);
  k_hpart<<<dim3(SEG_, B_), 256, 0, stream>>>(tok, embh, A);
  k_v    <<<dim3(8, B_),    256, 0, stream>>>(A, Wb, v);
  k_flash<<<dim3(SEG_, B_), 256, 0, stream>>>(tok, embh, v, A, ms);
  k_merge<<<B_,             256, 0, stream>>>(A, ms, out);
}